// Round 10
// baseline (145.528 us; speedup 1.0000x reference)
//
#include <hip/hip_runtime.h>
#include <hip/hip_bf16.h>

// ModulatedDeformConv2d forward: bf16 NHWC x, XCD-swizzled,
// producer/consumer wave-specialized fused sample+MFMA.
// R10: R6 structure (no register prefetch - proven futile R5/R8/R9), but
// 4 wgs/CU via __launch_bounds__(512,8) for cross-wg latency hiding, and
// packed f32x2 (v_pk_fma_f32) bilinear blend to cut producer VALU.
// x[8,64,128,128] f32, offset[8,18,128,128], mask[8,9,128,128],
// weight[64,64,3,3], bias[64]; out[8,64,128,128] f32.

constexpr int B    = 8;
constexpr int C    = 64;
constexpr int H    = 128;
constexpr int W    = 128;
constexpr int COUT = 64;
constexpr int K2   = 9;
constexpr int HW   = H * W;
constexpr int TPX  = 64;   // pixels per tile

typedef __attribute__((ext_vector_type(8))) short bf16x8;
typedef __attribute__((ext_vector_type(4))) float f32x4;
typedef __attribute__((ext_vector_type(2))) float f32x2;

// LDS tile row: 64 ch padded to 72 shorts (144 B).
constexpr int LDSS = 72;

// Raw workgroup barrier: drain LDS ops only (no vmcnt(0) drain).
#define LDS_BARRIER() asm volatile("s_waitcnt lgkmcnt(0)\n\ts_barrier" ::: "memory")

// ---------- x: NCHW f32 -> NHWC bf16 ----------
__global__ __launch_bounds__(256) void transpose_x_kernel(
    const float* __restrict__ x, short* __restrict__ xt) {
    __shared__ float tbuf[64][65];
    const int blk  = blockIdx.x;          // B * (HW/64) = 2048
    const int b    = blk >> 8;
    const int hwb  = (blk & 255) * 64;
    const int lane = threadIdx.x & 63;
    const int grp  = threadIdx.x >> 6;    // 0..3
    const float* xb = x + (size_t)b * C * HW;
#pragma unroll
    for (int r = 0; r < 16; ++r) {
        const int c = grp * 16 + r;
        tbuf[c][lane] = xb[c * HW + hwb + lane];   // coalesced along hw
    }
    __syncthreads();
    short* xo = xt + (size_t)b * HW * C;
#pragma unroll
    for (int r = 0; r < 16; ++r) {
        const int hw_l = grp * 16 + r;
        union { __hip_bfloat16 h; short s; } u;
        u.h = __float2bfloat16(tbuf[lane][hw_l]);
        xo[(size_t)(hwb + hw_l) * C + lane] = u.s;  // coalesced along c
    }
}

// ---------- weight[o][c][3][3] f32 -> A-fragment-ordered bf16 ----------
// wfrag[(k*8 + kk*4 + mt)*64 + lane][j] = bf16( w[m][c][k] )
//   m = mt*16 + (lane&15), q = lane>>4, c = kk*32 + q*8 + j
__global__ __launch_bounds__(256) void pack_w_kernel(
    const float* __restrict__ w, short* __restrict__ wfrag) {
    int id = blockIdx.x * blockDim.x + threadIdx.x;
    if (id >= COUT * C * K2) return;
    const int j    = id & 7;
    const int lane = (id >> 3) & 63;
    const int mt   = (id >> 9) & 3;
    const int kk   = (id >> 11) & 1;
    const int k    = id >> 12;
    const int m    = mt * 16 + (lane & 15);
    const int q    = lane >> 4;
    const int c    = kk * 32 + q * 8 + j;
    union { __hip_bfloat16 h; short s; } u;
    u.h = __float2bfloat16(w[(m * C + c) * K2 + k]);
    wfrag[id] = u.s;
}

// ---------- producer/consumer fused kernel ----------
// grid 2048: b = wg&7 (XCD round-robin -> per-XCD-L2-resident bf16 x),
// t = wg>>3 -> (ho, 64-px half-row). 512 threads = 8 waves; 4 wgs/CU.
__global__ __launch_bounds__(512, 8) void mdcn_pc_kernel(
    const short* __restrict__ xt,      // [B][H][W][C] bf16
    const float* __restrict__ offset,
    const float* __restrict__ mask,
    const short* __restrict__ wfrag,
    const float* __restrict__ bias,
    float* __restrict__ out) {

    __shared__ short smem[2][TPX * LDSS];    // 2 x 9216 B
    __shared__ float offs[2 * K2 * TPX];     // 4608 B
    __shared__ float msks[K2 * TPX];         // 2304 B

    const int wg   = blockIdx.x;
    const int b    = wg & 7;
    const int t    = wg >> 3;                // 0..255
    const int ho   = t >> 1;
    const int px0  = (t & 1) * TPX;

    const int tid  = threadIdx.x;
    const int wave = tid >> 6;

    // ---- stage per-tile offsets/masks (all 8 waves help) ----
    for (int f = tid; f < 2 * K2 * TPX; f += 512) {
        const int ch = f >> 6, i = f & 63;
        offs[f] = offset[(((size_t)b * 2 * K2 + ch) * H + ho) * W + px0 + i];
    }
    for (int f = tid; f < K2 * TPX; f += 512) {
        const int ch = f >> 6, i = f & 63;
        msks[f] = mask[(((size_t)b * K2 + ch) * H + ho) * W + px0 + i];
    }
    __syncthreads();                         // init barrier (full fence, once)

    if (wave < 4) {
        // ================= PRODUCER: sample -> LDS =================
        const int spx = tid >> 2;            // 0..63 pixel in tile
        const int cq  = (tid & 3) * 16;      // 16-channel quarter
        const int wo  = px0 + spx;
        const short* xb = xt + (size_t)b * HW * C;

        for (int k = 0; k < K2; ++k) {
            const int ky = k / 3, kx = k % 3;
            const float dx = offs[(2 * k    ) * TPX + spx];
            const float dy = offs[(2 * k + 1) * TPX + spx];
            const float mm = msks[k * TPX + spx];
            const float py = (float)(ho - 1 + ky) + dy;
            const float px = (float)(wo - 1 + kx) + dx;
            const float y0f = floorf(py), x0f = floorf(px);
            const float wy1 = py - y0f,   wx1 = px - x0f;
            const float wy0 = 1.0f - wy1, wx0 = 1.0f - wx1;
            const int iy0 = (int)y0f, ix0 = (int)x0f;
            const int iy1 = iy0 + 1,  ix1 = ix0 + 1;
            const bool vy0 = (iy0 >= 0) & (iy0 < H);
            const bool vy1 = (iy1 >= 0) & (iy1 < H);
            const bool vx0 = (ix0 >= 0) & (ix0 < W);
            const bool vx1 = (ix1 >= 0) & (ix1 < W);
            const float w00 = (vy0 & vx0) ? wy0 * wx0 * mm : 0.0f;
            const float w01 = (vy0 & vx1) ? wy0 * wx1 * mm : 0.0f;
            const float w10 = (vy1 & vx0) ? wy1 * wx0 * mm : 0.0f;
            const float w11 = (vy1 & vx1) ? wy1 * wx1 * mm : 0.0f;
            const int cy0 = min(max(iy0, 0), H - 1);
            const int cy1 = min(max(iy1, 0), H - 1);
            const int cx0 = min(max(ix0, 0), W - 1);
            const int cx1 = min(max(ix1, 0), W - 1);
            const short* s00 = xb + (cy0 * W + cx0) * C + cq;
            const short* s01 = xb + (cy0 * W + cx1) * C + cq;
            const short* s10 = xb + (cy1 * W + cx0) * C + cq;
            const short* s11 = xb + (cy1 * W + cx1) * C + cq;

            short* dst = &smem[k & 1][spx * LDSS + cq];
#pragma unroll
            for (int h = 0; h < 2; ++h) {    // two 8-channel halves
                const bf16x8 g00 = *(const bf16x8*)(s00 + h * 8);
                const bf16x8 g01 = *(const bf16x8*)(s01 + h * 8);
                const bf16x8 g10 = *(const bf16x8*)(s10 + h * 8);
                const bf16x8 g11 = *(const bf16x8*)(s11 + h * 8);
                union U8 { bf16x8 s; __hip_bfloat162 h2[4]; };
                U8 u00{g00}, u01{g01}, u10{g10}, u11{g11}, rr;
#pragma unroll
                for (int p = 0; p < 4; ++p) {
                    const float2 a00 = __bfloat1622float2(u00.h2[p]);
                    const float2 a01 = __bfloat1622float2(u01.h2[p]);
                    const float2 a10 = __bfloat1622float2(u10.h2[p]);
                    const float2 a11 = __bfloat1622float2(u11.h2[p]);
                    // packed f32x2 math -> v_pk_fma_f32
                    f32x2 f00 = {a00.x, a00.y}, f01 = {a01.x, a01.y};
                    f32x2 f10 = {a10.x, a10.y}, f11 = {a11.x, a11.y};
                    f32x2 v = f00 * w00 + f01 * w01 + f10 * w10 + f11 * w11;
                    rr.h2[p] = __float22bfloat162_rn(float2{v.x, v.y});
                }
                *(bf16x8*)(dst + h * 8) = rr.s;
            }
            // tile k ready: drain ds_write (lgkm) only.
            LDS_BARRIER();
        }
    } else {
        // ================= CONSUMER: LDS -> MFMA =================
        const int widx = wave - 4;           // 0..3
        const int lane = tid & 63;
        const int col  = lane & 15;
        const int q    = lane >> 4;
        const int pix  = widx * 16 + col;    // tile-local pixel
        const bf16x8* wf = (const bf16x8*)wfrag;

        f32x4 acc[4];
#pragma unroll
        for (int mt = 0; mt < 4; ++mt) acc[mt] = (f32x4)0.0f;

        for (int k = 0; k < K2; ++k) {
            LDS_BARRIER();                   // wait tile k
            bf16x8 af[8];
#pragma unroll
            for (int i = 0; i < 8; ++i) af[i] = wf[(k * 8 + i) * 64 + lane];
#pragma unroll
            for (int kk = 0; kk < 2; ++kk) {
                const bf16x8 bfrag =
                    *(const bf16x8*)(&smem[k & 1][pix * LDSS + kk * 32 + q * 8]);
#pragma unroll
                for (int mt = 0; mt < 4; ++mt)
                    acc[mt] = __builtin_amdgcn_mfma_f32_16x16x32_bf16(
                        af[kk * 4 + mt], bfrag, acc[mt], 0, 0, 0);
            }
        }

        // ---- epilogue: D row=(q*4+r) -> o, col -> px ----
        const int wo = px0 + pix;
#pragma unroll
        for (int mt = 0; mt < 4; ++mt) {
#pragma unroll
            for (int r = 0; r < 4; ++r) {
                const int o = mt * 16 + q * 4 + r;
                out[(((size_t)b * COUT + o) * H + ho) * W + wo] =
                    acc[mt][r] + bias[o];
            }
        }
    }
}

// ---------- fallback (direct, no workspace) ----------
__global__ __launch_bounds__(256) void mdcn_direct_kernel(
    const float* __restrict__ x, const float* __restrict__ offset,
    const float* __restrict__ mask, const float* __restrict__ wsrc,
    const float* __restrict__ bias, float* __restrict__ out) {
    const int p  = blockIdx.x * blockDim.x + threadIdx.x;
    const int wo = p & (W - 1);
    const int ho = (p >> 7) & (H - 1);
    const int b  = p >> 14;
    float acc[COUT];
#pragma unroll
    for (int o = 0; o < COUT; ++o) acc[o] = bias[o];
    const float* xb = x + b * C * HW;
    for (int k = 0; k < K2; ++k) {
        const int ky = k / 3, kx = k % 3;
        const float dx = offset[((b * 2 * K2 + 2 * k    ) * H + ho) * W + wo];
        const float dy = offset[((b * 2 * K2 + 2 * k + 1) * H + ho) * W + wo];
        const float m  = mask  [((b * K2     + k        ) * H + ho) * W + wo];
        const float py = (float)(ho - 1 + ky) + dy;
        const float px = (float)(wo - 1 + kx) + dx;
        const float y0f = floorf(py), x0f = floorf(px);
        const float wy1 = py - y0f, wx1 = px - x0f;
        const float wy0 = 1.0f - wy1, wx0 = 1.0f - wx1;
        const int iy0 = (int)y0f, ix0 = (int)x0f;
        const int iy1 = iy0 + 1, ix1 = ix0 + 1;
        const bool vy0 = (iy0 >= 0) & (iy0 < H);
        const bool vy1 = (iy1 >= 0) & (iy1 < H);
        const bool vx0 = (ix0 >= 0) & (ix0 < W);
        const bool vx1 = (ix1 >= 0) & (ix1 < W);
        const float w00 = (vy0 & vx0) ? wy0 * wx0 * m : 0.0f;
        const float w01 = (vy0 & vx1) ? wy0 * wx1 * m : 0.0f;
        const float w10 = (vy1 & vx0) ? wy1 * wx0 * m : 0.0f;
        const float w11 = (vy1 & vx1) ? wy1 * wx1 * m : 0.0f;
        const int cy0 = min(max(iy0, 0), H - 1);
        const int cy1 = min(max(iy1, 0), H - 1);
        const int cx0 = min(max(ix0, 0), W - 1);
        const int cx1 = min(max(ix1, 0), W - 1);
        const int o00 = cy0 * W + cx0, o01 = cy0 * W + cx1;
        const int o10 = cy1 * W + cx0, o11 = cy1 * W + cx1;
        for (int c = 0; c < C; ++c) {
            const float* xp = xb + c * HW;
            const float val = w00 * xp[o00] + w01 * xp[o01] +
                              w10 * xp[o10] + w11 * xp[o11];
#pragma unroll
            for (int o = 0; o < COUT; ++o)
                acc[o] += wsrc[(o * C + c) * K2 + k] * val;
        }
    }
    float* op = out + ((size_t)b * COUT) * HW + ho * W + wo;
#pragma unroll
    for (int o = 0; o < COUT; ++o) op[o * HW] = acc[o];
}

extern "C" void kernel_launch(void* const* d_in, const int* in_sizes, int n_in,
                              void* d_out, int out_size, void* d_ws, size_t ws_size,
                              hipStream_t stream) {
    const float* x      = (const float*)d_in[0];
    const float* offset = (const float*)d_in[1];
    const float* mask   = (const float*)d_in[2];
    const float* weight = (const float*)d_in[3];
    const float* bias   = (const float*)d_in[4];
    float* out          = (float*)d_out;

    const size_t xt_bytes = (size_t)B * HW * C * sizeof(short);   // 16.78 MB
    const size_t wf_bytes = (size_t)COUT * C * K2 * sizeof(short);
    if (ws_size >= xt_bytes + wf_bytes) {
        short* xt    = (short*)d_ws;
        short* wfrag = (short*)((char*)d_ws + xt_bytes);
        transpose_x_kernel<<<B * (HW / 64), 256, 0, stream>>>(x, xt);
        pack_w_kernel<<<(COUT * C * K2 + 255) / 256, 256, 0, stream>>>(weight, wfrag);
        mdcn_pc_kernel<<<2 * B * H, 512, 0, stream>>>(xt, offset, mask, wfrag, bias, out);
    } else {
        mdcn_direct_kernel<<<(B * HW) / 256, 256, 0, stream>>>(
            x, offset, mask, weight, bias, out);
    }
}

// Round 11
// 142.252 us; speedup vs baseline: 1.0230x; 1.0230x over previous
//
#include <hip/hip_runtime.h>
#include <hip/hip_bf16.h>

// ModulatedDeformConv2d forward: bf16 NHWC x, XCD-swizzled,
// producer/consumer wave-specialized fused sample+MFMA.
// R11: all 9 taps' sampling params (4 corner byte-offsets + 4 blend weights
// per pixel) are precomputed once into LDS by all 8 waves at init. Producer
// per-tap body shrinks to: ds_read params -> 8 gathers -> blend -> ds_write.
// x[8,64,128,128] f32, offset[8,18,128,128], mask[8,9,128,128],
// weight[64,64,3,3], bias[64]; out[8,64,128,128] f32.

constexpr int B    = 8;
constexpr int C    = 64;
constexpr int H    = 128;
constexpr int W    = 128;
constexpr int COUT = 64;
constexpr int K2   = 9;
constexpr int HW   = H * W;
constexpr int TPX  = 64;   // pixels per tile

typedef __attribute__((ext_vector_type(8))) short bf16x8;
typedef __attribute__((ext_vector_type(4))) float f32x4;
typedef __attribute__((ext_vector_type(2))) float f32x2;

// LDS tile row: 64 ch padded to 72 shorts (144 B).
constexpr int LDSS = 72;

// Raw workgroup barrier: drain LDS ops only (no vmcnt(0) drain).
#define LDS_BARRIER() asm volatile("s_waitcnt lgkmcnt(0)\n\ts_barrier" ::: "memory")

// ---------- x: NCHW f32 -> NHWC bf16 ----------
__global__ __launch_bounds__(256) void transpose_x_kernel(
    const float* __restrict__ x, short* __restrict__ xt) {
    __shared__ float tbuf[64][65];
    const int blk  = blockIdx.x;          // B * (HW/64) = 2048
    const int b    = blk >> 8;
    const int hwb  = (blk & 255) * 64;
    const int lane = threadIdx.x & 63;
    const int grp  = threadIdx.x >> 6;    // 0..3
    const float* xb = x + (size_t)b * C * HW;
#pragma unroll
    for (int r = 0; r < 16; ++r) {
        const int c = grp * 16 + r;
        tbuf[c][lane] = xb[c * HW + hwb + lane];   // coalesced along hw
    }
    __syncthreads();
    short* xo = xt + (size_t)b * HW * C;
#pragma unroll
    for (int r = 0; r < 16; ++r) {
        const int hw_l = grp * 16 + r;
        union { __hip_bfloat16 h; short s; } u;
        u.h = __float2bfloat16(tbuf[lane][hw_l]);
        xo[(size_t)(hwb + hw_l) * C + lane] = u.s;  // coalesced along c
    }
}

// ---------- weight[o][c][3][3] f32 -> A-fragment-ordered bf16 ----------
// wfrag[(k*8 + kk*4 + mt)*64 + lane][j] = bf16( w[m][c][k] )
//   m = mt*16 + (lane&15), q = lane>>4, c = kk*32 + q*8 + j
__global__ __launch_bounds__(256) void pack_w_kernel(
    const float* __restrict__ w, short* __restrict__ wfrag) {
    int id = blockIdx.x * blockDim.x + threadIdx.x;
    if (id >= COUT * C * K2) return;
    const int j    = id & 7;
    const int lane = (id >> 3) & 63;
    const int mt   = (id >> 9) & 3;
    const int kk   = (id >> 11) & 1;
    const int k    = id >> 12;
    const int m    = mt * 16 + (lane & 15);
    const int q    = lane >> 4;
    const int c    = kk * 32 + q * 8 + j;
    union { __hip_bfloat16 h; short s; } u;
    u.h = __float2bfloat16(w[(m * C + c) * K2 + k]);
    wfrag[id] = u.s;
}

// ---------- producer/consumer fused kernel ----------
// grid 2048: b = wg&7 (XCD round-robin -> per-XCD-L2-resident bf16 x),
// t = wg>>3 -> (ho, 64-px half-row). 512 threads = 8 waves.
__global__ __launch_bounds__(512, 4) void mdcn_pc_kernel(
    const short* __restrict__ xt,      // [B][H][W][C] bf16
    const float* __restrict__ offset,
    const float* __restrict__ mask,
    const short* __restrict__ wfrag,
    const float* __restrict__ bias,
    float* __restrict__ out) {

    __shared__ short smem[2][TPX * LDSS];    // 2 x 9216 B
    __shared__ int4   pidx[K2 * TPX];        // 9216 B: 4 corner byte-offsets
    __shared__ float4 pwts[K2 * TPX];        // 9216 B: 4 blend weights

    const int wg   = blockIdx.x;
    const int b    = wg & 7;
    const int t    = wg >> 3;                // 0..255
    const int ho   = t >> 1;
    const int px0  = (t & 1) * TPX;

    const int tid  = threadIdx.x;
    const int wave = tid >> 6;

    // ---- precompute ALL taps' sampling params (one thread per (tap,px)) ----
    for (int f = tid; f < K2 * TPX; f += 512) {
        const int k = f >> 6;                // tap
        const int i = f & 63;                // tile-local pixel
        const int wo = px0 + i;
        const int ky = k / 3, kx = k % 3;
        const float dx = offset[(((size_t)b * 2 * K2 + 2 * k    ) * H + ho) * W + wo];
        const float dy = offset[(((size_t)b * 2 * K2 + 2 * k + 1) * H + ho) * W + wo];
        const float mm = mask  [(((size_t)b * K2     + k        ) * H + ho) * W + wo];
        const float py = (float)(ho - 1 + ky) + dy;
        const float px = (float)(wo - 1 + kx) + dx;
        const float y0f = floorf(py), x0f = floorf(px);
        const float wy1 = py - y0f,   wx1 = px - x0f;
        const float wy0 = 1.0f - wy1, wx0 = 1.0f - wx1;
        const int iy0 = (int)y0f, ix0 = (int)x0f;
        const int iy1 = iy0 + 1,  ix1 = ix0 + 1;
        const bool vy0 = (iy0 >= 0) & (iy0 < H);
        const bool vy1 = (iy1 >= 0) & (iy1 < H);
        const bool vx0 = (ix0 >= 0) & (ix0 < W);
        const bool vx1 = (ix1 >= 0) & (ix1 < W);
        float4 wv;
        wv.x = (vy0 & vx0) ? wy0 * wx0 * mm : 0.0f;
        wv.y = (vy0 & vx1) ? wy0 * wx1 * mm : 0.0f;
        wv.z = (vy1 & vx0) ? wy1 * wx0 * mm : 0.0f;
        wv.w = (vy1 & vx1) ? wy1 * wx1 * mm : 0.0f;
        const int cy0 = min(max(iy0, 0), H - 1);
        const int cy1 = min(max(iy1, 0), H - 1);
        const int cx0 = min(max(ix0, 0), W - 1);
        const int cx1 = min(max(ix1, 0), W - 1);
        int4 bv;                              // byte offsets into xb
        bv.x = (cy0 * W + cx0) * (C * 2);
        bv.y = (cy0 * W + cx1) * (C * 2);
        bv.z = (cy1 * W + cx0) * (C * 2);
        bv.w = (cy1 * W + cx1) * (C * 2);
        pidx[f] = bv;
        pwts[f] = wv;
    }
    __syncthreads();                         // init barrier (full fence, once)

    if (wave < 4) {
        // ================= PRODUCER: sample -> LDS =================
        const int spx = tid >> 2;            // 0..63 pixel in tile
        const int cq  = (tid & 3) * 16;      // 16-channel quarter
        const char* xb =
            (const char*)(xt + (size_t)b * HW * C) + cq * 2;

        for (int k = 0; k < K2; ++k) {
            const int4   bi = pidx[k * 64 + spx];   // ds_read_b128 (4-px bcast)
            const float4 wv = pwts[k * 64 + spx];
            const short* s00 = (const short*)(xb + bi.x);
            const short* s01 = (const short*)(xb + bi.y);
            const short* s10 = (const short*)(xb + bi.z);
            const short* s11 = (const short*)(xb + bi.w);

            short* dst = &smem[k & 1][spx * LDSS + cq];
#pragma unroll
            for (int h = 0; h < 2; ++h) {    // two 8-channel halves
                const bf16x8 g00 = *(const bf16x8*)(s00 + h * 8);
                const bf16x8 g01 = *(const bf16x8*)(s01 + h * 8);
                const bf16x8 g10 = *(const bf16x8*)(s10 + h * 8);
                const bf16x8 g11 = *(const bf16x8*)(s11 + h * 8);
                union U8 { bf16x8 s; __hip_bfloat162 h2[4]; };
                U8 u00{g00}, u01{g01}, u10{g10}, u11{g11}, rr;
#pragma unroll
                for (int p = 0; p < 4; ++p) {
                    const float2 a00 = __bfloat1622float2(u00.h2[p]);
                    const float2 a01 = __bfloat1622float2(u01.h2[p]);
                    const float2 a10 = __bfloat1622float2(u10.h2[p]);
                    const float2 a11 = __bfloat1622float2(u11.h2[p]);
                    f32x2 f00 = {a00.x, a00.y}, f01 = {a01.x, a01.y};
                    f32x2 f10 = {a10.x, a10.y}, f11 = {a11.x, a11.y};
                    f32x2 v = f00 * wv.x + f01 * wv.y + f10 * wv.z + f11 * wv.w;
                    rr.h2[p] = __float22bfloat162_rn(float2{v.x, v.y});
                }
                *(bf16x8*)(dst + h * 8) = rr.s;
            }
            LDS_BARRIER();                   // tile k ready (lgkm drain only)
        }
    } else {
        // ================= CONSUMER: LDS -> MFMA =================
        const int widx = wave - 4;           // 0..3
        const int lane = tid & 63;
        const int col  = lane & 15;
        const int q    = lane >> 4;
        const int pix  = widx * 16 + col;    // tile-local pixel
        const bf16x8* wf = (const bf16x8*)wfrag;

        f32x4 acc[4];
#pragma unroll
        for (int mt = 0; mt < 4; ++mt) acc[mt] = (f32x4)0.0f;

        for (int k = 0; k < K2; ++k) {
            LDS_BARRIER();                   // wait tile k
            bf16x8 af[8];
#pragma unroll
            for (int i = 0; i < 8; ++i) af[i] = wf[(k * 8 + i) * 64 + lane];
#pragma unroll
            for (int kk = 0; kk < 2; ++kk) {
                const bf16x8 bfrag =
                    *(const bf16x8*)(&smem[k & 1][pix * LDSS + kk * 32 + q * 8]);
#pragma unroll
                for (int mt = 0; mt < 4; ++mt)
                    acc[mt] = __builtin_amdgcn_mfma_f32_16x16x32_bf16(
                        af[kk * 4 + mt], bfrag, acc[mt], 0, 0, 0);
            }
        }

        // ---- epilogue: D row=(q*4+r) -> o, col -> px ----
        const int wo = px0 + pix;
#pragma unroll
        for (int mt = 0; mt < 4; ++mt) {
#pragma unroll
            for (int r = 0; r < 4; ++r) {
                const int o = mt * 16 + q * 4 + r;
                out[(((size_t)b * COUT + o) * H + ho) * W + wo] =
                    acc[mt][r] + bias[o];
            }
        }
    }
}

// ---------- fallback (direct, no workspace) ----------
__global__ __launch_bounds__(256) void mdcn_direct_kernel(
    const float* __restrict__ x, const float* __restrict__ offset,
    const float* __restrict__ mask, const float* __restrict__ wsrc,
    const float* __restrict__ bias, float* __restrict__ out) {
    const int p  = blockIdx.x * blockDim.x + threadIdx.x;
    const int wo = p & (W - 1);
    const int ho = (p >> 7) & (H - 1);
    const int b  = p >> 14;
    float acc[COUT];
#pragma unroll
    for (int o = 0; o < COUT; ++o) acc[o] = bias[o];
    const float* xb = x + b * C * HW;
    for (int k = 0; k < K2; ++k) {
        const int ky = k / 3, kx = k % 3;
        const float dx = offset[((b * 2 * K2 + 2 * k    ) * H + ho) * W + wo];
        const float dy = offset[((b * 2 * K2 + 2 * k + 1) * H + ho) * W + wo];
        const float m  = mask  [((b * K2     + k        ) * H + ho) * W + wo];
        const float py = (float)(ho - 1 + ky) + dy;
        const float px = (float)(wo - 1 + kx) + dx;
        const float y0f = floorf(py), x0f = floorf(px);
        const float wy1 = py - y0f, wx1 = px - x0f;
        const float wy0 = 1.0f - wy1, wx0 = 1.0f - wx1;
        const int iy0 = (int)y0f, ix0 = (int)x0f;
        const int iy1 = iy0 + 1, ix1 = ix0 + 1;
        const bool vy0 = (iy0 >= 0) & (iy0 < H);
        const bool vy1 = (iy1 >= 0) & (iy1 < H);
        const bool vx0 = (ix0 >= 0) & (ix0 < W);
        const bool vx1 = (ix1 >= 0) & (ix1 < W);
        const float w00 = (vy0 & vx0) ? wy0 * wx0 * m : 0.0f;
        const float w01 = (vy0 & vx1) ? wy0 * wx1 * m : 0.0f;
        const float w10 = (vy1 & vx0) ? wy1 * wx0 * m : 0.0f;
        const float w11 = (vy1 & vx1) ? wy1 * wx1 * m : 0.0f;
        const int cy0 = min(max(iy0, 0), H - 1);
        const int cy1 = min(max(iy1, 0), H - 1);
        const int cx0 = min(max(ix0, 0), W - 1);
        const int cx1 = min(max(ix1, 0), W - 1);
        const int o00 = cy0 * W + cx0, o01 = cy0 * W + cx1;
        const int o10 = cy1 * W + cx0, o11 = cy1 * W + cx1;
        for (int c = 0; c < C; ++c) {
            const float* xp = xb + c * HW;
            const float val = w00 * xp[o00] + w01 * xp[o01] +
                              w10 * xp[o10] + w11 * xp[o11];
#pragma unroll
            for (int o = 0; o < COUT; ++o)
                acc[o] += wsrc[(o * C + c) * K2 + k] * val;
        }
    }
    float* op = out + ((size_t)b * COUT) * HW + ho * W + wo;
#pragma unroll
    for (int o = 0; o < COUT; ++o) op[o * HW] = acc[o];
}

extern "C" void kernel_launch(void* const* d_in, const int* in_sizes, int n_in,
                              void* d_out, int out_size, void* d_ws, size_t ws_size,
                              hipStream_t stream) {
    const float* x      = (const float*)d_in[0];
    const float* offset = (const float*)d_in[1];
    const float* mask   = (const float*)d_in[2];
    const float* weight = (const float*)d_in[3];
    const float* bias   = (const float*)d_in[4];
    float* out          = (float*)d_out;

    const size_t xt_bytes = (size_t)B * HW * C * sizeof(short);   // 16.78 MB
    const size_t wf_bytes = (size_t)COUT * C * K2 * sizeof(short);
    if (ws_size >= xt_bytes + wf_bytes) {
        short* xt    = (short*)d_ws;
        short* wfrag = (short*)((char*)d_ws + xt_bytes);
        transpose_x_kernel<<<B * (HW / 64), 256, 0, stream>>>(x, xt);
        pack_w_kernel<<<(COUT * C * K2 + 255) / 256, 256, 0, stream>>>(weight, wfrag);
        mdcn_pc_kernel<<<2 * B * H, 512, 0, stream>>>(xt, offset, mask, wfrag, bias, out);
    } else {
        mdcn_direct_kernel<<<(B * HW) / 256, 256, 0, stream>>>(
            x, offset, mask, weight, bias, out);
    }
}